// Round 2
// baseline (810.926 us; speedup 1.0000x reference)
//
#include <hip/hip_runtime.h>
#include <hip/hip_bf16.h>
#include <math.h>

#define HH 2048
#define SZ ((size_t)HH * HH)
#define BM 128
#define BN 128
#define BK 32
#define LDT 40   // LDS row stride (elements): 32 + 8 pad, keeps 16B alignment

typedef __bf16 bf16x8 __attribute__((ext_vector_type(8)));
typedef float f32x4 __attribute__((ext_vector_type(4)));

__device__ __forceinline__ unsigned short f2b(float f) {
    unsigned int u = __float_as_uint(f);
    unsigned int r = (u + 0x7FFFu + ((u >> 16) & 1u)) >> 16;   // RNE
    return (unsigned short)r;
}
__device__ __forceinline__ float b2f(unsigned short u) {
    return __uint_as_float(((unsigned int)u) << 16);
}
__device__ __forceinline__ unsigned int pack2(float a, float b) {
    return (unsigned int)f2b(a) | ((unsigned int)f2b(b) << 16);
}

// ---------------------------------------------------------------- conversion
struct CvtArgs { const float* src[12]; };

__global__ __launch_bounds__(256) void cvt_kernel(CvtArgs args, unsigned short* dst) {
    const float* s = args.src[blockIdx.y];
    size_t i = ((size_t)blockIdx.x * 256 + threadIdx.x) * 8;
    const float4* s4 = reinterpret_cast<const float4*>(s + i);
    float4 v0 = s4[0], v1 = s4[1];
    uint4 o;
    o.x = pack2(v0.x, v0.y); o.y = pack2(v0.z, v0.w);
    o.z = pack2(v1.x, v1.y); o.w = pack2(v1.z, v1.w);
    *reinterpret_cast<uint4*>(dst + (size_t)blockIdx.y * SZ + i) = o;
}

// ---------------------------------------------------------------- GEMM core
// C[M,N] += A[M,K] @ B[K,N]; A,B bf16 row-major, all dims 2048.
// 256 threads = 4 waves in 2x2, each wave owns a 64x64 output sub-tile.
__device__ __forceinline__ void gemm_tile_acc(
    const unsigned short* __restrict__ A,
    const unsigned short* __restrict__ B,
    unsigned short* lds_a, unsigned short* lds_b,
    f32x4 (&acc)[4][4], int bm, int bn)
{
    const int tid  = threadIdx.x;
    const int lane = tid & 63;
    const int w    = tid >> 6;
    const int wr   = w >> 1, wc = w & 1;

    for (int k0 = 0; k0 < HH; k0 += BK) {
        // stage A tile [BM][BK] row-major, vectorized 16B
        #pragma unroll
        for (int it = 0; it < 2; ++it) {
            int flat = (it * 256 + tid) * 8;      // 0..4095
            int row  = flat >> 5;                 // /BK
            int col  = flat & 31;
            uint4 v = *reinterpret_cast<const uint4*>(A + (size_t)(bm + row) * HH + k0 + col);
            *reinterpret_cast<uint4*>(lds_a + row * LDT + col) = v;
        }
        // stage B tile transposed: lds_b[n][k'], k' = k ^ ((n>>3 & 3)<<3) swizzle
        #pragma unroll
        for (int it = 0; it < 2; ++it) {
            int flat = (it * 256 + tid) * 8;
            int krow = flat >> 7;                 // /BN -> 0..31
            int ncol = flat & 127;
            uint4 v = *reinterpret_cast<const uint4*>(B + (size_t)(k0 + krow) * HH + bn + ncol);
            int kk = krow ^ (((ncol >> 3) & 3) << 3);
            const unsigned short* pv = reinterpret_cast<const unsigned short*>(&v);
            #pragma unroll
            for (int j = 0; j < 8; ++j)
                lds_b[(ncol + j) * LDT + kk] = pv[j];
        }
        __syncthreads();

        bf16x8 af[4], bfr[4];
        #pragma unroll
        for (int m = 0; m < 4; ++m) {
            int r = wr * 64 + m * 16 + (lane & 15);
            af[m] = *reinterpret_cast<const bf16x8*>(lds_a + r * LDT + (lane >> 4) * 8);
        }
        #pragma unroll
        for (int n = 0; n < 4; ++n) {
            int c  = wc * 64 + n * 16 + (lane & 15);
            int kg = (lane >> 4) ^ ((c >> 3) & 3);
            bfr[n] = *reinterpret_cast<const bf16x8*>(lds_b + c * LDT + kg * 8);
        }
        #pragma unroll
        for (int m = 0; m < 4; ++m) {
            #pragma unroll
            for (int n = 0; n < 4; ++n)
                acc[m][n] = __builtin_amdgcn_mfma_f32_16x16x32_bf16(af[m], bfr[n], acc[m][n], 0, 0, 0);
        }
        __syncthreads();
    }
}

// epilogue: C/D frag mapping col=lane&15, row=(lane>>4)*4+reg  [guide m89]
__device__ __forceinline__ void epilogue(
    f32x4 (&acc)[4][4], int bm, int bn,
    const float* bias, float* outF, unsigned short* outB, int act)
{
    const int tid  = threadIdx.x;
    const int lane = tid & 63;
    const int w    = tid >> 6;
    const int wr   = w >> 1, wc = w & 1;
    #pragma unroll
    for (int m = 0; m < 4; ++m) {
        #pragma unroll
        for (int n = 0; n < 4; ++n) {
            int col = bn + wc * 64 + n * 16 + (lane & 15);
            float bv = bias ? bias[col] : 0.0f;
            #pragma unroll
            for (int r4 = 0; r4 < 4; ++r4) {
                int row = bm + wr * 64 + m * 16 + (lane >> 4) * 4 + r4;
                float vv = acc[m][n][r4] + bv;
                if (outF) outF[(size_t)row * HH + col] = vv;
                if (outB) outB[(size_t)row * HH + col] = f2b(act ? tanhf(vv) : vv);
            }
        }
    }
}

// stage 1: Z_g = bf16(h @ W_hg + x @ W_xg + b_xg), all 4 gates in one launch
struct Stage1Args {
    const unsigned short* Ah; const unsigned short* Ax;
    const unsigned short* WH[4]; const unsigned short* WX[4];
    const float* bias[4];
    unsigned short* Z[4];
};

__global__ __launch_bounds__(256) void gemm_stage1(Stage1Args a) {
    __shared__ unsigned short lds_a[BM * LDT];
    __shared__ unsigned short lds_b[BN * LDT];
    int g  = blockIdx.z;
    int bm = blockIdx.y * BM, bn = blockIdx.x * BN;
    f32x4 acc[4][4];
    #pragma unroll
    for (int m = 0; m < 4; ++m)
        #pragma unroll
        for (int n = 0; n < 4; ++n) { f32x4 z = {0.f, 0.f, 0.f, 0.f}; acc[m][n] = z; }
    gemm_tile_acc(a.Ah, a.WH[g], lds_a, lds_b, acc, bm, bn);
    gemm_tile_acc(a.Ax, a.WX[g], lds_a, lds_b, acc, bm, bn);
    epilogue(acc, bm, bn, a.bias[g], nullptr, a.Z[g], 0);
}

// generic: out = A0@B0 (+ A1@B1) (+bias); optional f32 store + bf16(act) store
struct GemmArgs {
    const unsigned short* A0; const unsigned short* B0;
    const unsigned short* A1; const unsigned short* B1;
    int npairs;
    const float* bias;
    float* outF;
    unsigned short* outB;
    int act;   // 0 identity, 1 tanh (applied to bf16 copy only)
};

__global__ __launch_bounds__(256) void gemm_generic(GemmArgs a) {
    __shared__ unsigned short lds_a[BM * LDT];
    __shared__ unsigned short lds_b[BN * LDT];
    int bm = blockIdx.y * BM, bn = blockIdx.x * BN;
    f32x4 acc[4][4];
    #pragma unroll
    for (int m = 0; m < 4; ++m)
        #pragma unroll
        for (int n = 0; n < 4; ++n) { f32x4 z = {0.f, 0.f, 0.f, 0.f}; acc[m][n] = z; }
    gemm_tile_acc(a.A0, a.B0, lds_a, lds_b, acc, bm, bn);
    if (a.npairs > 1)
        gemm_tile_acc(a.A1, a.B1, lds_a, lds_b, acc, bm, bn);
    epilogue(acc, bm, bn, a.bias, a.outF, a.outB, a.act);
}

// ---------------------------------------------------------------- LayerNorm + act
struct LNArgs {
    const unsigned short* Z[4];
    const float* gamma[4];
    const float* beta[4];
    unsigned short* out[4];
};

__global__ __launch_bounds__(256) void ln_kernel(LNArgs a) {
    int gate = blockIdx.y;
    int row  = blockIdx.x;
    const unsigned short* z = a.Z[gate] + (size_t)row * HH;
    int t = threadIdx.x;
    uint4 v = *reinterpret_cast<const uint4*>(z + t * 8);
    unsigned int wv[4] = {v.x, v.y, v.z, v.w};
    float x[8];
    #pragma unroll
    for (int j = 0; j < 4; ++j) {
        x[2 * j]     = b2f((unsigned short)(wv[j] & 0xFFFFu));
        x[2 * j + 1] = b2f((unsigned short)(wv[j] >> 16));
    }
    float s = 0.f, ss = 0.f;
    #pragma unroll
    for (int j = 0; j < 8; ++j) { s += x[j]; ss += x[j] * x[j]; }
    for (int o = 32; o > 0; o >>= 1) { s += __shfl_down(s, o); ss += __shfl_down(ss, o); }
    __shared__ float red[8];
    int wv_i = t >> 6, lane = t & 63;
    if (lane == 0) { red[wv_i] = s; red[4 + wv_i] = ss; }
    __syncthreads();
    float S  = red[0] + red[1] + red[2] + red[3];
    float SS = red[4] + red[5] + red[6] + red[7];
    float mean = S * (1.0f / HH);
    float var  = SS * (1.0f / HH) - mean * mean;
    float rs   = rsqrtf(var + 1e-5f);
    const float* gm = a.gamma[gate];
    const float* bt = a.beta[gate];
    unsigned int o4[4];
    #pragma unroll
    for (int j = 0; j < 4; ++j) {
        int c0 = t * 8 + 2 * j;
        float y0 = (x[2 * j] - mean) * rs * gm[c0] + bt[c0];
        float y1 = (x[2 * j + 1] - mean) * rs * gm[c0 + 1] + bt[c0 + 1];
        float r0, r1;
        if (gate == 1) { r0 = tanhf(y0); r1 = tanhf(y1); }
        else           { r0 = 1.f / (1.f + expf(-y0)); r1 = 1.f / (1.f + expf(-y1)); }
        o4[j] = pack2(r0, r1);
    }
    uint4 ov; ov.x = o4[0]; ov.y = o4[1]; ov.z = o4[2]; ov.w = o4[3];
    *reinterpret_cast<uint4*>(a.out[gate] + (size_t)row * HH + t * 8) = ov;
}

// ---------------------------------------------------------------- launch
// ws slots (each SZ bf16 = 8 MiB), lifetimes overlapped; peak = 16 slots = 128 MiB:
//  0 h_bf, 1 x_bf, 2 c_bf, 3..6 W_hf..W_ho, 7..10 W_xf..W_xo, 11 W_y
//  12..15 Z_f..Z_o (bf16, stage-1 output)
//  after LN: f_t->3, g_t->4, i_t->5, o_t->6  (W_h* dead)
//  tanh(c_t)_bf16 -> 7, h_bf16 -> 8          (W_xf/W_xg dead)
extern "C" void kernel_launch(void* const* d_in, const int* in_sizes, int n_in,
                              void* d_out, int out_size, void* d_ws, size_t ws_size,
                              hipStream_t stream) {
    (void)in_sizes; (void)n_in; (void)out_size; (void)ws_size;
    const float* F[25];
    for (int i = 0; i < 25; ++i) F[i] = (const float*)d_in[i];
    unsigned short* ws = (unsigned short*)d_ws;
    auto slot = [&](int s) { return ws + (size_t)s * SZ; };
    float* out = (float*)d_out;

    // 1) fp32 -> bf16 conversions (one launch, 12 tensors)
    CvtArgs ca;
    ca.src[0] = F[2];   // h_states
    ca.src[1] = F[0];   // inputs
    ca.src[2] = F[1];   // c_states
    ca.src[3] = F[3]; ca.src[4] = F[4]; ca.src[5] = F[5]; ca.src[6] = F[6];     // W_h*
    ca.src[7] = F[7]; ca.src[8] = F[8]; ca.src[9] = F[9]; ca.src[10] = F[10];   // W_x*
    ca.src[11] = F[15]; // W_y
    cvt_kernel<<<dim3(SZ / (256 * 8), 12), dim3(256), 0, stream>>>(ca, ws);

    // 2) gate pre-activations Z_g = h@W_hg + x@W_xg + b_xg   (grid.z = gate)
    Stage1Args s1;
    s1.Ah = slot(0); s1.Ax = slot(1);
    for (int g = 0; g < 4; ++g) {
        s1.WH[g]   = slot(3 + g);
        s1.WX[g]   = slot(7 + g);
        s1.bias[g] = F[11 + g];
        s1.Z[g]    = slot(12 + g);
    }
    gemm_stage1<<<dim3(16, 16, 4), dim3(256), 0, stream>>>(s1);

    // 3) LayerNorm + activation per gate -> bf16 gates (into dead W_h* slots)
    LNArgs ln;
    for (int g = 0; g < 4; ++g) { ln.Z[g] = slot(12 + g); ln.out[g] = slot(3 + g); }
    ln.gamma[0] = F[17]; ln.beta[0] = F[18];
    ln.gamma[1] = F[19]; ln.beta[1] = F[20];
    ln.gamma[2] = F[21]; ln.beta[2] = F[22];
    ln.gamma[3] = F[23]; ln.beta[3] = F[24];
    ln_kernel<<<dim3(HH, 4), dim3(256), 0, stream>>>(ln);

    // 4) c_t = f@c + g@i ; also tanh(c_t) -> bf16 slot 7
    GemmArgs gc;
    gc.A0 = slot(3); gc.B0 = slot(2);
    gc.A1 = slot(4); gc.B1 = slot(5);
    gc.npairs = 2; gc.bias = nullptr;
    gc.outF = out; gc.outB = slot(7); gc.act = 1;
    gemm_generic<<<dim3(16, 16), dim3(256), 0, stream>>>(gc);

    // 5) h_t = tanh(c_t) @ o ; bf16 copy -> slot 8
    GemmArgs gh;
    gh.A0 = slot(7); gh.B0 = slot(6);
    gh.A1 = nullptr; gh.B1 = nullptr;
    gh.npairs = 1; gh.bias = nullptr;
    gh.outF = out + SZ; gh.outB = slot(8); gh.act = 0;
    gemm_generic<<<dim3(16, 16), dim3(256), 0, stream>>>(gh);

    // 6) y = h @ W_y + b_y
    GemmArgs gy;
    gy.A0 = slot(8); gy.B0 = slot(11);
    gy.A1 = nullptr; gy.B1 = nullptr;
    gy.npairs = 1; gy.bias = F[16];
    gy.outF = out + 2 * SZ; gy.outB = nullptr; gy.act = 0;
    gemm_generic<<<dim3(16, 16), dim3(256), 0, stream>>>(gy);
}

// Round 3
// 620.571 us; speedup vs baseline: 1.3067x; 1.3067x over previous
//
#include <hip/hip_runtime.h>
#include <hip/hip_bf16.h>
#include <math.h>

#define HH 2048
#define SZ ((size_t)HH * HH)

typedef __bf16 bf16x8 __attribute__((ext_vector_type(8)));
typedef float f32x4 __attribute__((ext_vector_type(4)));

__device__ __forceinline__ unsigned short f2b(float f) {
    unsigned int u = __float_as_uint(f);
    unsigned int r = (u + 0x7FFFu + ((u >> 16) & 1u)) >> 16;   // RNE
    return (unsigned short)r;
}
__device__ __forceinline__ float b2f(unsigned short u) {
    return __uint_as_float(((unsigned int)u) << 16);
}
__device__ __forceinline__ unsigned int pack2(float a, float b) {
    return (unsigned int)f2b(a) | ((unsigned int)f2b(b) << 16);
}

// async global->LDS, 16B per lane; LDS dest is wave-uniform base + lane*16
__device__ __forceinline__ void glds16(const unsigned short* g, unsigned short* l) {
    __builtin_amdgcn_global_load_lds(
        (const __attribute__((address_space(1))) unsigned int*)g,
        (__attribute__((address_space(3))) unsigned int*)l, 16, 0, 0);
}

// ---------------------------------------------------------------- conversions
struct CvtArgs { const float* src[2]; };

__global__ __launch_bounds__(256) void cvt_plain(CvtArgs args, unsigned short* dst) {
    const float* s = args.src[blockIdx.y];
    size_t i = ((size_t)blockIdx.x * 256 + threadIdx.x) * 8;
    const float4* s4 = reinterpret_cast<const float4*>(s + i);
    float4 v0 = s4[0], v1 = s4[1];
    uint4 o;
    o.x = pack2(v0.x, v0.y); o.y = pack2(v0.z, v0.w);
    o.z = pack2(v1.x, v1.y); o.w = pack2(v1.z, v1.w);
    *reinterpret_cast<uint4*>(dst + (size_t)blockIdx.y * SZ + i) = o;
}

// fp32 -> bf16 with transpose: dst[n][k] = src[k][n], via 64x64 LDS tile
struct CvtTArgs { const float* src[10]; unsigned short* dst[10]; };

__global__ __launch_bounds__(256) void cvt_t(CvtTArgs a) {
    __shared__ unsigned short lds[64 * 72];
    const float* src = a.src[blockIdx.z];
    unsigned short* dst = a.dst[blockIdx.z];
    int i0 = blockIdx.y * 64, j0 = blockIdx.x * 64;
    int t = threadIdx.x;
    #pragma unroll
    for (int it = 0; it < 2; ++it) {
        int row = it * 32 + (t >> 3);
        int col = (t & 7) * 8;
        const float4* p = reinterpret_cast<const float4*>(src + (size_t)(i0 + row) * HH + j0 + col);
        float4 v0 = p[0], v1 = p[1];
        float x[8] = {v0.x, v0.y, v0.z, v0.w, v1.x, v1.y, v1.z, v1.w};
        #pragma unroll
        for (int j = 0; j < 8; ++j) lds[row * 72 + col + j] = f2b(x[j]);
    }
    __syncthreads();
    #pragma unroll
    for (int it = 0; it < 2; ++it) {
        int rp = it * 32 + (t >> 3);      // out row within tile (= src col)
        int cp = (t & 7) * 8;             // out col within tile (= src row)
        unsigned short vals[8];
        #pragma unroll
        for (int j = 0; j < 8; ++j) vals[j] = lds[(cp + j) * 72 + rp];
        *reinterpret_cast<uint4*>(dst + (size_t)(j0 + rp) * HH + i0 + cp) =
            *reinterpret_cast<uint4*>(vals);
    }
}

// bf16 transpose (for LN outputs feeding the B side)
struct TrArgs { const unsigned short* src[2]; unsigned short* dst[2]; };

__global__ __launch_bounds__(256) void transpose_bf(TrArgs a) {
    __shared__ unsigned short lds[64 * 72];
    const unsigned short* src = a.src[blockIdx.z];
    unsigned short* dst = a.dst[blockIdx.z];
    int i0 = blockIdx.y * 64, j0 = blockIdx.x * 64;
    int t = threadIdx.x;
    #pragma unroll
    for (int it = 0; it < 2; ++it) {
        int row = it * 32 + (t >> 3);
        int col = (t & 7) * 8;
        uint4 v = *reinterpret_cast<const uint4*>(src + (size_t)(i0 + row) * HH + j0 + col);
        const unsigned short* pv = reinterpret_cast<const unsigned short*>(&v);
        #pragma unroll
        for (int j = 0; j < 8; ++j) lds[row * 72 + col + j] = pv[j];
    }
    __syncthreads();
    #pragma unroll
    for (int it = 0; it < 2; ++it) {
        int rp = it * 32 + (t >> 3);
        int cp = (t & 7) * 8;
        unsigned short vals[8];
        #pragma unroll
        for (int j = 0; j < 8; ++j) vals[j] = lds[(cp + j) * 72 + rp];
        *reinterpret_cast<uint4*>(dst + (size_t)(j0 + rp) * HH + i0 + cp) =
            *reinterpret_cast<uint4*>(vals);
    }
}

// ---------------------------------------------------------------- GEMM core (m97 structure)
// C[M,N] += A[M,K] @ B[K,N], B supplied TRANSPOSED (Bt[N][K] row-major).
// 128x128 tile, BK=32, 256 thr = 4 waves (2x2), wave sub-tile 64x64, acc[4][4].
// Staging: global_load_lds 16B/lane into linear LDS [128][32].
__device__ __forceinline__ void pass97(const unsigned short* __restrict__ A,
                                       const unsigned short* __restrict__ Bt,
                                       unsigned short* lds_a, unsigned short* lds_b,
                                       f32x4 (&acc)[4][4], int bm, int bn, int klen)
{
    const int tid  = threadIdx.x;
    const int lane = tid & 63;
    const int w    = tid >> 6;
    const int wr   = w >> 1, wc = w & 1;
    const int srow = w * 16 + (lane >> 2);     // 0..63
    const int scol = (lane & 3) * 8;           // 0..24
    const unsigned short* pa = A  + (size_t)(bm + srow) * HH + scol;
    const unsigned short* pb = Bt + (size_t)(bn + srow) * HH + scol;
    unsigned short* la = lds_a + w * 512;      // wave-uniform LDS dest
    unsigned short* lb = lds_b + w * 512;

    for (int k0 = 0; k0 < klen; k0 += 32) {
        __syncthreads();                       // prev compute done before overwrite
        glds16(pa + k0,           la);
        glds16(pa + 64 * HH + k0, la + 2048);
        glds16(pb + k0,           lb);
        glds16(pb + 64 * HH + k0, lb + 2048);
        __syncthreads();                       // drains vmcnt -> tile ready

        bf16x8 af[4], bf[4];
        const int kg = (lane >> 4) * 8;
        #pragma unroll
        for (int m = 0; m < 4; ++m)
            af[m] = *reinterpret_cast<const bf16x8*>(lds_a + (wr * 64 + m * 16 + (lane & 15)) * 32 + kg);
        #pragma unroll
        for (int n = 0; n < 4; ++n)
            bf[n] = *reinterpret_cast<const bf16x8*>(lds_b + (wc * 64 + n * 16 + (lane & 15)) * 32 + kg);
        #pragma unroll
        for (int m = 0; m < 4; ++m)
            #pragma unroll
            for (int n = 0; n < 4; ++n)
                acc[m][n] = __builtin_amdgcn_mfma_f32_16x16x32_bf16(af[m], bf[n], acc[m][n], 0, 0, 0);
    }
}

// stage 1: Z_g = bf16(h @ W_hg + x @ W_xg + b_xg); grid (16,16,4)
struct S1Args {
    const unsigned short* Ah; const unsigned short* Ax;
    const unsigned short* WHt[4]; const unsigned short* WXt[4];
    const float* bias[4];
    unsigned short* Z[4];
};

__global__ __launch_bounds__(256) void gemm_s1(S1Args a) {
    __shared__ unsigned short lds_a[128 * 32];
    __shared__ unsigned short lds_b[128 * 32];
    int g = blockIdx.z, bm = blockIdx.y * 128, bn = blockIdx.x * 128;
    f32x4 acc[4][4];
    #pragma unroll
    for (int m = 0; m < 4; ++m)
        #pragma unroll
        for (int n = 0; n < 4; ++n) { f32x4 z = {0.f, 0.f, 0.f, 0.f}; acc[m][n] = z; }
    pass97(a.Ah, a.WHt[g], lds_a, lds_b, acc, bm, bn, HH);
    pass97(a.Ax, a.WXt[g], lds_a, lds_b, acc, bm, bn, HH);
    // epilogue: C/D frag col=lane&15, row=(lane>>4)*4+reg
    const int tid = threadIdx.x, lane = tid & 63, w = tid >> 6;
    const int wr = w >> 1, wc = w & 1;
    const float* bias = a.bias[g];
    unsigned short* Z = a.Z[g];
    #pragma unroll
    for (int m = 0; m < 4; ++m)
        #pragma unroll
        for (int n = 0; n < 4; ++n) {
            int col = bn + wc * 64 + n * 16 + (lane & 15);
            float bv = bias[col];
            #pragma unroll
            for (int r = 0; r < 4; ++r) {
                int row = bm + wr * 64 + m * 16 + (lane >> 4) * 4 + r;
                Z[(size_t)row * HH + col] = f2b(acc[m][n][r] + bv);
            }
        }
}

// split-K GEMM: z selects (A, Bt, partial buffer); writes raw f32 partials
struct SKArgs {
    const unsigned short* A[4]; const unsigned short* Bt[4];
    float* P[4];
    int klen;
};

__global__ __launch_bounds__(256) void gemm_sk(SKArgs a) {
    __shared__ unsigned short lds_a[128 * 32];
    __shared__ unsigned short lds_b[128 * 32];
    int z = blockIdx.z, bm = blockIdx.y * 128, bn = blockIdx.x * 128;
    f32x4 acc[4][4];
    #pragma unroll
    for (int m = 0; m < 4; ++m)
        #pragma unroll
        for (int n = 0; n < 4; ++n) { f32x4 zz = {0.f, 0.f, 0.f, 0.f}; acc[m][n] = zz; }
    pass97(a.A[z], a.Bt[z], lds_a, lds_b, acc, bm, bn, a.klen);
    const int tid = threadIdx.x, lane = tid & 63, w = tid >> 6;
    const int wr = w >> 1, wc = w & 1;
    float* P = a.P[z];
    #pragma unroll
    for (int m = 0; m < 4; ++m)
        #pragma unroll
        for (int n = 0; n < 4; ++n) {
            int col = bn + wc * 64 + n * 16 + (lane & 15);
            #pragma unroll
            for (int r = 0; r < 4; ++r) {
                int row = bm + wr * 64 + m * 16 + (lane >> 4) * 4 + r;
                P[(size_t)row * HH + col] = acc[m][n][r];
            }
        }
}

// combine: sum np partials (+bias), write f32 out (+ optional bf16(act) copy)
struct CArgs {
    const float* P[4]; int np;
    const float* bias;
    float* outF;
    unsigned short* outB;
    int act;   // 1 = tanh on bf16 copy
};

__global__ __launch_bounds__(256) void combine(CArgs a) {
    size_t i = ((size_t)blockIdx.x * 256 + threadIdx.x) * 4;
    float4 s = *reinterpret_cast<const float4*>(a.P[0] + i);
    for (int j = 1; j < a.np; ++j) {
        float4 v = *reinterpret_cast<const float4*>(a.P[j] + i);
        s.x += v.x; s.y += v.y; s.z += v.z; s.w += v.w;
    }
    if (a.bias) {
        float4 b = *reinterpret_cast<const float4*>(a.bias + (i & (size_t)(HH - 1)));
        s.x += b.x; s.y += b.y; s.z += b.z; s.w += b.w;
    }
    *reinterpret_cast<float4*>(a.outF + i) = s;
    if (a.outB) {
        float t0 = s.x, t1 = s.y, t2 = s.z, t3 = s.w;
        if (a.act) { t0 = tanhf(t0); t1 = tanhf(t1); t2 = tanhf(t2); t3 = tanhf(t3); }
        uint2 o; o.x = pack2(t0, t1); o.y = pack2(t2, t3);
        *reinterpret_cast<uint2*>(a.outB + i) = o;
    }
}

// ---------------------------------------------------------------- LayerNorm + act
struct LNArgs {
    const unsigned short* Z[4];
    const float* gamma[4];
    const float* beta[4];
    unsigned short* out[4];
};

__global__ __launch_bounds__(256) void ln_kernel(LNArgs a) {
    int gate = blockIdx.y;
    int row  = blockIdx.x;
    const unsigned short* z = a.Z[gate] + (size_t)row * HH;
    int t = threadIdx.x;
    uint4 v = *reinterpret_cast<const uint4*>(z + t * 8);
    unsigned int wv[4] = {v.x, v.y, v.z, v.w};
    float x[8];
    #pragma unroll
    for (int j = 0; j < 4; ++j) {
        x[2 * j]     = b2f((unsigned short)(wv[j] & 0xFFFFu));
        x[2 * j + 1] = b2f((unsigned short)(wv[j] >> 16));
    }
    float s = 0.f, ss = 0.f;
    #pragma unroll
    for (int j = 0; j < 8; ++j) { s += x[j]; ss += x[j] * x[j]; }
    for (int o = 32; o > 0; o >>= 1) { s += __shfl_down(s, o); ss += __shfl_down(ss, o); }
    __shared__ float red[8];
    int wv_i = t >> 6, lane = t & 63;
    if (lane == 0) { red[wv_i] = s; red[4 + wv_i] = ss; }
    __syncthreads();
    float S  = red[0] + red[1] + red[2] + red[3];
    float SS = red[4] + red[5] + red[6] + red[7];
    float mean = S * (1.0f / HH);
    float var  = SS * (1.0f / HH) - mean * mean;
    float rs   = rsqrtf(var + 1e-5f);
    const float* gm = a.gamma[gate];
    const float* bt = a.beta[gate];
    unsigned int o4[4];
    #pragma unroll
    for (int j = 0; j < 4; ++j) {
        int c0 = t * 8 + 2 * j;
        float y0 = (x[2 * j] - mean) * rs * gm[c0] + bt[c0];
        float y1 = (x[2 * j + 1] - mean) * rs * gm[c0 + 1] + bt[c0 + 1];
        float r0, r1;
        if (gate == 1) { r0 = tanhf(y0); r1 = tanhf(y1); }
        else           { r0 = 1.f / (1.f + expf(-y0)); r1 = 1.f / (1.f + expf(-y1)); }
        o4[j] = pack2(r0, r1);
    }
    uint4 ov; ov.x = o4[0]; ov.y = o4[1]; ov.z = o4[2]; ov.w = o4[3];
    *reinterpret_cast<uint4*>(a.out[gate] + (size_t)row * HH + t * 8) = ov;
}

// ---------------------------------------------------------------- launch
// ws slots (bf16, 8 MiB each), peak index 15 = 128 MiB:
//  0 h, 1 x, 2 c^T, 3..6 W_h{f,g,i,o}^T, 7..10 W_x{f,g,i,o}^T, 11 W_y^T
//  12..15 Z_{f,g,i,o}
//  after LN (W_h^T dead):      f->3, g->4, i->5, o->6
//  transposes (W_xi/xo^T dead): i^T->9, o^T->10
//  f32 partials in dead slots:  pairs (0,1),(7,8),(12,13),(14,15)
//  tanh(c)->3 (f dead), h_bf->4 (g dead)
extern "C" void kernel_launch(void* const* d_in, const int* in_sizes, int n_in,
                              void* d_out, int out_size, void* d_ws, size_t ws_size,
                              hipStream_t stream) {
    (void)in_sizes; (void)n_in; (void)out_size; (void)ws_size;
    const float* F[25];
    for (int i = 0; i < 25; ++i) F[i] = (const float*)d_in[i];
    unsigned short* ws = (unsigned short*)d_ws;
    auto slot  = [&](int s) { return ws + (size_t)s * SZ; };
    auto slotF = [&](int s) { return (float*)(ws + (size_t)s * SZ); };
    float* out = (float*)d_out;

    // 1) plain cvt: h_states->0, inputs->1
    CvtArgs ca; ca.src[0] = F[2]; ca.src[1] = F[0];
    cvt_plain<<<dim3(SZ / (256 * 8), 2), dim3(256), 0, stream>>>(ca, ws);

    // 2) transposing cvt: c^T->2, W_h*^T->3..6, W_x*^T->7..10, W_y^T->11
    CvtTArgs ct;
    ct.src[0] = F[1];  ct.dst[0] = slot(2);
    for (int g = 0; g < 4; ++g) { ct.src[1 + g] = F[3 + g]; ct.dst[1 + g] = slot(3 + g); }
    for (int g = 0; g < 4; ++g) { ct.src[5 + g] = F[7 + g]; ct.dst[5 + g] = slot(7 + g); }
    ct.src[9] = F[15]; ct.dst[9] = slot(11);
    cvt_t<<<dim3(32, 32, 10), dim3(256), 0, stream>>>(ct);

    // 3) stage 1: Z_g = bf16(h@W_hg + x@W_xg + b_xg) -> slots 12..15
    S1Args s1;
    s1.Ah = slot(0); s1.Ax = slot(1);
    for (int g = 0; g < 4; ++g) {
        s1.WHt[g] = slot(3 + g); s1.WXt[g] = slot(7 + g);
        s1.bias[g] = F[11 + g];  s1.Z[g] = slot(12 + g);
    }
    gemm_s1<<<dim3(16, 16, 4), dim3(256), 0, stream>>>(s1);

    // 4) LN + activation -> f,g,i,o in slots 3..6
    LNArgs ln;
    for (int g = 0; g < 4; ++g) { ln.Z[g] = slot(12 + g); ln.out[g] = slot(3 + g); }
    ln.gamma[0] = F[17]; ln.beta[0] = F[18];
    ln.gamma[1] = F[19]; ln.beta[1] = F[20];
    ln.gamma[2] = F[21]; ln.beta[2] = F[22];
    ln.gamma[3] = F[23]; ln.beta[3] = F[24];
    ln_kernel<<<dim3(HH, 4), dim3(256), 0, stream>>>(ln);

    // 5) transpose i->i^T (slot 9), o->o^T (slot 10)
    TrArgs tr;
    tr.src[0] = slot(5); tr.dst[0] = slot(9);
    tr.src[1] = slot(6); tr.dst[1] = slot(10);
    transpose_bf<<<dim3(32, 32, 2), dim3(256), 0, stream>>>(tr);

    // 6) c_t = f@c + g@i, split-K x4 -> f32 partials
    SKArgs sc;
    sc.A[0] = slot(3);        sc.Bt[0] = slot(2);        sc.P[0] = slotF(0);
    sc.A[1] = slot(3) + 1024; sc.Bt[1] = slot(2) + 1024; sc.P[1] = slotF(7);
    sc.A[2] = slot(4);        sc.Bt[2] = slot(9);        sc.P[2] = slotF(12);
    sc.A[3] = slot(4) + 1024; sc.Bt[3] = slot(9) + 1024; sc.P[3] = slotF(14);
    sc.klen = 1024;
    gemm_sk<<<dim3(16, 16, 4), dim3(256), 0, stream>>>(sc);

    // 7) combine c: out f32 + tanh(c) bf16 -> slot 3
    CArgs cc;
    cc.P[0] = slotF(0); cc.P[1] = slotF(7); cc.P[2] = slotF(12); cc.P[3] = slotF(14);
    cc.np = 4; cc.bias = nullptr; cc.outF = out; cc.outB = slot(3); cc.act = 1;
    combine<<<dim3(SZ / 1024), dim3(256), 0, stream>>>(cc);

    // 8) h_t = tanh(c) @ o, split-K x2
    SKArgs sh;
    sh.A[0] = slot(3);        sh.Bt[0] = slot(10);        sh.P[0] = slotF(0);
    sh.A[1] = slot(3) + 1024; sh.Bt[1] = slot(10) + 1024; sh.P[1] = slotF(7);
    sh.A[2] = slot(3);        sh.Bt[2] = slot(10);        sh.P[2] = slotF(0);  // unused
    sh.A[3] = slot(3);        sh.Bt[3] = slot(10);        sh.P[3] = slotF(7);  // unused
    sh.klen = 1024;
    gemm_sk<<<dim3(16, 16, 2), dim3(256), 0, stream>>>(sh);

    // 9) combine h: out f32 + bf16 copy -> slot 4
    CArgs ch;
    ch.P[0] = slotF(0); ch.P[1] = slotF(7); ch.P[2] = nullptr; ch.P[3] = nullptr;
    ch.np = 2; ch.bias = nullptr; ch.outF = out + SZ; ch.outB = slot(4); ch.act = 0;
    combine<<<dim3(SZ / 1024), dim3(256), 0, stream>>>(ch);

    // 10) y = h @ W_y + b_y, split-K x2
    SKArgs sy;
    sy.A[0] = slot(4);        sy.Bt[0] = slot(11);        sy.P[0] = slotF(0);
    sy.A[1] = slot(4) + 1024; sy.Bt[1] = slot(11) + 1024; sy.P[1] = slotF(7);
    sy.A[2] = slot(4);        sy.Bt[2] = slot(11);        sy.P[2] = slotF(0);  // unused
    sy.A[3] = slot(4);        sy.Bt[3] = slot(11);        sy.P[3] = slotF(7);  // unused
    sy.klen = 1024;
    gemm_sk<<<dim3(16, 16, 2), dim3(256), 0, stream>>>(sy);

    // 11) combine y: + b_y, f32 out only
    CArgs cy;
    cy.P[0] = slotF(0); cy.P[1] = slotF(7); cy.P[2] = nullptr; cy.P[3] = nullptr;
    cy.np = 2; cy.bias = F[16]; cy.outF = out + 2 * SZ; cy.outB = nullptr; cy.act = 0;
    combine<<<dim3(SZ / 1024), dim3(256), 0, stream>>>(cy);
}